// Round 7
// baseline (162.422 us; speedup 1.0000x reference)
//
#include <hip/hip_runtime.h>
#include <hip/hip_bf16.h>
#include <cstdint>
#include <cstddef>

#define B_ 2
#define N_ 2048
#define D_ 256
#define H_ 8
#define HID_ 64
#define EN_ 2
#define ALPHA 0.2f
#define NEGBIG (-3.0e38f)
#define LOG2E 1.4426950408889634f

typedef __bf16 bf16x8 __attribute__((ext_vector_type(8)));
typedef float f32x4 __attribute__((ext_vector_type(4)));
typedef unsigned short ushort8 __attribute__((ext_vector_type(8)));
typedef float float4v __attribute__((ext_vector_type(4)));
typedef float float2v __attribute__((ext_vector_type(2)));

__device__ __forceinline__ unsigned short f2bf(float f) {
    unsigned int u = __builtin_bit_cast(unsigned int, f);
    unsigned int r = u + 0x7FFFu + ((u >> 16) & 1u);  // RNE
    return (unsigned short)(r >> 16);
}
__device__ __forceinline__ float leakyf(float x) { return fmaxf(x, ALPHA * x); }

// load 8 consecutive f32, convert to 8 bf16
__device__ __forceinline__ ushort8 cvt8(const float* __restrict__ p) {
    float4v x0 = *(const float4v*)p;
    float4v x1 = *(const float4v*)(p + 4);
    ushort8 r;
    #pragma unroll
    for (int e = 0; e < 4; ++e) { r[e] = f2bf(x0[e]); r[e + 4] = f2bf(x1[e]); }
    return r;
}

// ---------- K0: transpose W_att[h][d][o] f32 -> WT[h][o][d] bf16 (tiny) ----------
__global__ void k_transpose_w(const float* __restrict__ W,
                              unsigned short* __restrict__ WT) {
    int h = blockIdx.x;
    const float* Wh = W + (size_t)h * D_ * HID_;
    unsigned short* WTh = WT + (size_t)h * HID_ * D_;
    for (int idx = threadIdx.x; idx < D_ * HID_; idx += blockDim.x) {
        int d = idx / HID_, o = idx % HID_;
        WTh[o * D_ + d] = f2bf(Wh[idx]);
    }
}

// ---------- K1: wh = fea @ W_att (per b,h), fused e1/e2 (scaled by LOG2E) ----------
__global__ __launch_bounds__(256) void k_wh(
    const float* __restrict__ fea,            // [B][N][D] f32
    const unsigned short* __restrict__ WT,    // [H][64][256] bf16
    const float* __restrict__ a_att,          // [H][128] f32
    unsigned short* __restrict__ whT,         // [B][H][64][N] bf16
    float* __restrict__ e1, float* __restrict__ e2)
{
    int bid = blockIdx.x;
    int i0 = (bid & 31) << 6;
    int h  = (bid >> 5) & 7;
    int b  = bid >> 8;

    __shared__ __align__(16) union SmemA {
        struct { unsigned short fa[64 * 72]; unsigned short wt[64 * 72]; } s;
        float tr[64 * 65];
    } u;

    int t = threadIdx.x;
    int lane = t & 63;
    int wv = t >> 6;          // wave id 0..3
    int r = lane & 15, q = lane >> 4;
    int ra = t >> 2;          // staging row 0..63
    int cc = (t & 3) * 16;    // staging col chunk

    f32x4 acc[4] = {};

    const float* fearow = fea + ((size_t)(b * N_ + i0 + ra)) * D_;
    const unsigned short* wtrow = WT + ((size_t)(h * 64 + ra)) * D_;

    for (int d0 = 0; d0 < D_; d0 += 64) {
        *(ushort8*)&u.s.fa[ra * 72 + cc]     = cvt8(fearow + d0 + cc);
        *(ushort8*)&u.s.fa[ra * 72 + cc + 8] = cvt8(fearow + d0 + cc + 8);
        *(ushort8*)&u.s.wt[ra * 72 + cc]     = *(const ushort8*)(wtrow + d0 + cc);
        *(ushort8*)&u.s.wt[ra * 72 + cc + 8] = *(const ushort8*)(wtrow + d0 + cc + 8);
        __syncthreads();
        #pragma unroll
        for (int k0 = 0; k0 < 64; k0 += 32) {
            bf16x8 a = *(const bf16x8*)&u.s.fa[(16 * wv + r) * 72 + k0 + q * 8];
            #pragma unroll
            for (int f = 0; f < 4; ++f) {
                bf16x8 bb = *(const bf16x8*)&u.s.wt[(16 * f + r) * 72 + k0 + q * 8];
                acc[f] = __builtin_amdgcn_mfma_f32_16x16x32_bf16(a, bb, acc[f], 0, 0, 0);
            }
        }
        __syncthreads();
    }

    // e1/e2 epilogue (scaled by LOG2E for exp2-domain softmax downstream)
    float a1v[4], a2v[4];
    #pragma unroll
    for (int f = 0; f < 4; ++f) {
        a1v[f] = a_att[h * 128 + 16 * f + r];
        a2v[f] = a_att[h * 128 + 64 + 16 * f + r];
    }
    #pragma unroll
    for (int rr = 0; rr < 4; ++rr) {
        float s1 = 0.f, s2 = 0.f;
        #pragma unroll
        for (int f = 0; f < 4; ++f) { s1 += acc[f][rr] * a1v[f]; s2 += acc[f][rr] * a2v[f]; }
        #pragma unroll
        for (int m = 1; m < 16; m <<= 1) {
            s1 += __shfl_xor(s1, m, 64);
            s2 += __shfl_xor(s2, m, 64);
        }
        if (r == 0) {
            int i = i0 + 16 * wv + 4 * q + rr;
            size_t idx = ((size_t)(b * H_ + h)) * N_ + i;
            e1[idx] = s1 * LOG2E; e2[idx] = s2 * LOG2E;
        }
    }

    // transpose wh tile -> whT (via LDS)
    #pragma unroll
    for (int f = 0; f < 4; ++f)
        #pragma unroll
        for (int rr = 0; rr < 4; ++rr)
            u.tr[(16 * f + r) * 65 + 16 * wv + 4 * q + rr] = acc[f][rr];
    __syncthreads();
    {
        int o = t >> 2;
        int ch = (t & 3) * 16;
        unsigned short tmp[16];
        #pragma unroll
        for (int e = 0; e < 16; ++e) tmp[e] = f2bf(u.tr[o * 65 + ch + e]);
        ushort8* dst = (ushort8*)(whT + (((size_t)(b * H_ + h) * 64 + o)) * N_ + i0 + ch);
        dst[0] = *(ushort8*)&tmp[0];
        dst[1] = *(ushort8*)&tmp[8];
    }
}

// ---------- K2: maxE2[bh] = max_j e2[bh][j] (tiny) ----------
__global__ __launch_bounds__(256) void k_maxe2(const float* __restrict__ e2,
                                               float* __restrict__ mx) {
    int bh = blockIdx.x;
    int t = threadIdx.x;
    const float* row = e2 + (size_t)bh * N_;
    float M = NEGBIG;
    #pragma unroll
    for (int it = 0; it < N_ / 256; ++it) M = fmaxf(M, row[it * 256 + t]);
    #pragma unroll
    for (int s = 1; s < 64; s <<= 1) M = fmaxf(M, __shfl_xor(M, s, 64));
    __shared__ float red[4];
    if ((t & 63) == 0) red[t >> 6] = M;
    __syncthreads();
    if (t == 0) mx[bh] = fmaxf(fmaxf(red[0], red[1]), fmaxf(red[2], red[3]));
}

// ---------- K3: x_part[s] = P_chunk @ wh; BARRIER-FREE main loop ----------
// 4 waves x 16 rows = 64 i-rows per block. whT B-fragments loaded directly
// from global (L1/L2-resident; lane-contiguous 16B reads). e2 slice in LDS
// (prologue barrier only). adj register-prefetched 2 tiles deep.
template<int JPER>
__global__ __launch_bounds__(256, 4) void k_pv1(
    const float* __restrict__ adj,
    const unsigned short* __restrict__ whT,   // [B][H][64][N] bf16
    const float* __restrict__ e1g, const float* __restrict__ e2g,
    const float* __restrict__ maxE2,
    float* __restrict__ x_part,               // [S][B][N][512] f32
    float* __restrict__ zPart)                // [S][16][N] f32
{
    constexpr int NT = JPER / 64;
    int s  = blockIdx.x;
    int i0 = blockIdx.y << 6;                 // 64 rows per block
    int bh = blockIdx.z;                      // b*H + h
    int h = bh & 7, b = bh >> 3;
    int jBeg = s * JPER;

    __shared__ float e2s[JPER];               // e2 slice (2-8 KB)

    int t = threadIdx.x;
    int lane = t & 63;
    int wv = t >> 6;                          // 0..3
    int r = lane & 15, q = lane >> 4;

    int ir = i0 + 16 * wv + r;                // this lane's P row
    float eRow = e1g[(size_t)bh * N_ + ir];
    float m = leakyf(eRow + maxE2[bh]);       // upper bound >= masked row max
    float eRm = eRow - m;
    float eR2 = ALPHA * eRow - m;

    const float* e2p = e2g + (size_t)bh * N_ + jBeg;
    const float* ap  = adj + ((size_t)(b * N_ + ir)) * N_ + jBeg + q * 8;
    // B-fragment base per output block f: whT[bh*64 + f*16 + r][jBeg + q*8]
    const unsigned short* wp = whT + ((size_t)bh * 64 + r) * N_ + jBeg + q * 8;

    // stage e2 slice into LDS (only barrier in the kernel)
    for (int jj = t; jj < JPER; jj += 256) e2s[jj] = e2p[jj];
    __syncthreads();

    bf16x8 ones;
    #pragma unroll
    for (int e = 0; e < 8; ++e) ones[e] = (__bf16)1.0f;

    f32x4 acc[4] = {};
    f32x4 accz = {};

    // adj register pipeline, 2 tiles deep
    float4v aA[4], aB[4];

#define LOADADJ(A, tile) do {                                              \
        const float* ap_ = ap + (tile) * 64;                               \
        A[0] = *(const float4v*)(ap_);      A[1] = *(const float4v*)(ap_ + 4);  \
        A[2] = *(const float4v*)(ap_ + 32); A[3] = *(const float4v*)(ap_ + 36); \
    } while (0)

    LOADADJ(aA, 0);
    if (NT > 1) LOADADJ(aB, 1);

    // P-gen: exp2(leaky) * adj into MFMA A-fragments
    auto pgen = [&](const float4v* av, int t8, bf16x8& pa0, bf16x8& pa1) {
        const float* ejs = &e2s[t8 * 64 + q * 8];
        float4v f0 = *(const float4v*)(ejs);
        float4v f1 = *(const float4v*)(ejs + 4);
        float4v g0 = *(const float4v*)(ejs + 32);
        float4v g1 = *(const float4v*)(ejs + 36);
        #pragma unroll
        for (int e = 0; e < 4; ++e) {
            float p;
            p = __builtin_amdgcn_exp2f(fmaxf(eRm + f0[e], __builtin_fmaf(ALPHA, f0[e], eR2)));
            pa0[e] = (__bf16)(p * av[0][e]);
            p = __builtin_amdgcn_exp2f(fmaxf(eRm + f1[e], __builtin_fmaf(ALPHA, f1[e], eR2)));
            pa0[e + 4] = (__bf16)(p * av[1][e]);
            p = __builtin_amdgcn_exp2f(fmaxf(eRm + g0[e], __builtin_fmaf(ALPHA, g0[e], eR2)));
            pa1[e] = (__bf16)(p * av[2][e]);
            p = __builtin_amdgcn_exp2f(fmaxf(eRm + g1[e], __builtin_fmaf(ALPHA, g1[e], eR2)));
            pa1[e + 4] = (__bf16)(p * av[3][e]);
        }
    };

    #pragma unroll 2
    for (int t8 = 0; t8 < NT; ++t8) {
        const int cur = t8 & 1;
        // issue this tile's whT B-fragment loads first (latency hides under pgen)
        bf16x8 bb0[4], bb1[4];
        #pragma unroll
        for (int f = 0; f < 4; ++f) {
            bb0[f] = *(const bf16x8*)(wp + (size_t)f * 16 * N_ + t8 * 64);
            bb1[f] = *(const bf16x8*)(wp + (size_t)f * 16 * N_ + t8 * 64 + 32);
        }

        bf16x8 pa0, pa1;
        if (cur == 0) pgen(aA, t8, pa0, pa1);
        else          pgen(aB, t8, pa0, pa1);

        // issue adj loads for tile t8+2 into the just-freed register set
        if (t8 + 2 < NT) {
            if (cur == 0) LOADADJ(aA, t8 + 2);
            else          LOADADJ(aB, t8 + 2);
        }

        #pragma unroll
        for (int f = 0; f < 4; ++f)
            acc[f] = __builtin_amdgcn_mfma_f32_16x16x32_bf16(pa0, bb0[f], acc[f], 0, 0, 0);
        accz = __builtin_amdgcn_mfma_f32_16x16x32_bf16(pa0, ones, accz, 0, 0, 0);
        #pragma unroll
        for (int f = 0; f < 4; ++f)
            acc[f] = __builtin_amdgcn_mfma_f32_16x16x32_bf16(pa1, bb1[f], acc[f], 0, 0, 0);
        accz = __builtin_amdgcn_mfma_f32_16x16x32_bf16(pa1, ones, accz, 0, 0, 0);
    }
#undef LOADADJ

    // epilogue: raw partial write (elu + /Z happen in k_wh2)
    float* xp = x_part + ((size_t)s * (B_ * N_) + (size_t)b * N_) * 512 + h * 64;
    #pragma unroll
    for (int f = 0; f < 4; ++f) {
        #pragma unroll
        for (int rr = 0; rr < 4; ++rr) {
            int i = i0 + 16 * wv + 4 * q + rr;
            xp[(size_t)i * 512 + 16 * f + r] = acc[f][rr];
        }
    }
    if (r == 0) {
        #pragma unroll
        for (int rr = 0; rr < 4; ++rr) {
            int i = i0 + 16 * wv + 4 * q + rr;
            zPart[((size_t)(s * 16 + bh)) * N_ + i] = accz[rr];
        }
    }
}

// ---------- K4: x = elu(sum_s part / Z); wh2 = x @ W_last; g1/g2 scaled ----------
__global__ __launch_bounds__(256) void k_wh2(
    const float* __restrict__ x_part,
    const float* __restrict__ zPart,
    const float* __restrict__ W_last,  // [512][2] f32
    const float* __restrict__ a_last,  // [4] f32
    float* __restrict__ wh2, float* __restrict__ g1, float* __restrict__ g2,
    int S)
{
    int idx = blockIdx.x * 4 + (threadIdx.x >> 6);  // b*N + n
    int lane = threadIdx.x & 63;
    int b = idx >> 11, n = idx & (N_ - 1);
    float a0 = 0.f, a1 = 0.f;
    #pragma unroll
    for (int it = 0; it < 8; ++it) {        // it == head index
        int k = it * 64 + lane;
        float xv = 0.f, zv = 0.f;
        for (int s = 0; s < S; ++s) {
            xv += x_part[((size_t)s * (B_ * N_) + idx) * 512 + k];
            zv += zPart[((size_t)(s * 16 + b * 8 + it)) * N_ + n];
        }
        float x = (zv > 0.f) ? xv / zv : 0.f;
        x = x > 0.f ? x : expm1f(x);
        float2v wl = *(const float2v*)(W_last + k * 2);
        a0 += x * wl[0];
        a1 += x * wl[1];
    }
    #pragma unroll
    for (int s = 1; s < 64; s <<= 1) {
        a0 += __shfl_xor(a0, s, 64);
        a1 += __shfl_xor(a1, s, 64);
    }
    if (lane == 0) {
        wh2[idx * 2] = a0; wh2[idx * 2 + 1] = a1;
        g1[idx] = (a0 * a_last[0] + a1 * a_last[1]) * LOG2E;
        g2[idx] = (a0 * a_last[2] + a1 * a_last[3]) * LOG2E;
    }
}

// ---------- K5: final attention + elu, two-pass register version (exp2) ----------
__global__ __launch_bounds__(256) void k_out(
    const float* __restrict__ adj,
    const float* __restrict__ wh2,
    const float* __restrict__ g1, const float* __restrict__ g2,
    float* __restrict__ out)
{
    int idx = blockIdx.x * 4 + (threadIdx.x >> 6); // b*N + i
    int lane = threadIdx.x & 63;
    int b = idx >> 11;
    float gi = g1[idx];
    const float* arow = adj + (size_t)idx * N_;
    const float* g2b = g2 + (size_t)b * N_;
    const float* wh2b = wh2 + (size_t)b * N_ * 2;

    float ep[32];
    float M = NEGBIG;
    #pragma unroll
    for (int it = 0; it < 8; ++it) {
        int j = it * 256 + lane * 4;
        float4v a4 = *(const float4v*)(arow + j);
        float4v s4 = *(const float4v*)(g2b + j);
        #pragma unroll
        for (int e = 0; e < 4; ++e) {
            float l = leakyf(gi + s4[e]);
            float v = (a4[e] != 0.f) ? l : NEGBIG;
            ep[it * 4 + e] = v;
            M = fmaxf(M, v);
        }
    }
    #pragma unroll
    for (int s = 1; s < 64; s <<= 1) M = fmaxf(M, __shfl_xor(M, s, 64));

    float Z = 0.f, A0 = 0.f, A1 = 0.f;
    #pragma unroll
    for (int it = 0; it < 8; ++it) {
        int j = it * 256 + lane * 4;
        float4v wA = *(const float4v*)(wh2b + 2 * j);
        float4v wB = *(const float4v*)(wh2b + 2 * j + 4);
        #pragma unroll
        for (int e = 0; e < 4; ++e) {
            float p = __builtin_amdgcn_exp2f(ep[it * 4 + e] - M);
            Z += p;
            float w0 = (e < 2) ? wA[2 * e] : wB[2 * (e - 2)];
            float w1 = (e < 2) ? wA[2 * e + 1] : wB[2 * (e - 2) + 1];
            A0 += p * w0;
            A1 += p * w1;
        }
    }
    #pragma unroll
    for (int s = 1; s < 64; s <<= 1) {
        Z += __shfl_xor(Z, s, 64);
        A0 += __shfl_xor(A0, s, 64);
        A1 += __shfl_xor(A1, s, 64);
    }
    if (lane == 0) {
        float o0 = A0 / Z, o1 = A1 / Z;
        o0 = o0 > 0.f ? o0 : expm1f(o0);
        o1 = o1 > 0.f ? o1 : expm1f(o1);
        float2v ov; ov[0] = o0; ov[1] = o1;
        *(float2v*)(out + idx * 2) = ov;
    }
}

extern "C" void kernel_launch(void* const* d_in, const int* in_sizes, int n_in,
                              void* d_out, int out_size, void* d_ws, size_t ws_size,
                              hipStream_t stream) {
    const float* fea    = (const float*)d_in[0];
    const float* adj    = (const float*)d_in[1];
    const float* W_att  = (const float*)d_in[2];
    const float* a_att  = (const float*)d_in[3];
    const float* W_last = (const float*)d_in[4];
    const float* a_last = (const float*)d_in[5];

    char* ws = (char*)d_ws;
    // layout (bytes)
    float* e1  = (float*)(ws + 0);                            // 131,072
    float* e2  = (float*)(ws + 131072);                       // 131,072
    float* mxE = (float*)(ws + 262144);                       // 256 (pad)
    float* wh2 = (float*)(ws + 262400);                       // 32,768
    float* g1  = (float*)(ws + 295168);                       // 16,384
    float* g2  = (float*)(ws + 311552);                       // 16,384
    unsigned short* WT  = (unsigned short*)(ws + 327936);     // 262,144
    unsigned short* whT = (unsigned short*)(ws + 590080);     // 4,194,304
    float* zPart = (float*)(ws + 4784384);                    // 524,288 (S<=4)
    float* x_part = (float*)(ws + 5308672);                   // S * 8,388,608

    const size_t BASE = 5308672ULL, XPART = 8388608ULL;
    int S = (ws_size >= BASE + 4 * XPART) ? 4
          : (ws_size >= BASE + 2 * XPART) ? 2 : 1;

    k_transpose_w<<<dim3(H_), dim3(256), 0, stream>>>(W_att, WT);
    k_wh<<<dim3(B_ * H_ * (N_ / 64)), dim3(256), 0, stream>>>(
        fea, WT, a_att, whT, e1, e2);
    k_maxe2<<<dim3(B_ * H_), dim3(256), 0, stream>>>(e2, mxE);
    if (S == 4)
        k_pv1<512><<<dim3(4, N_ / 64, B_ * H_), dim3(256), 0, stream>>>(
            adj, whT, e1, e2, mxE, x_part, zPart);
    else if (S == 2)
        k_pv1<1024><<<dim3(2, N_ / 64, B_ * H_), dim3(256), 0, stream>>>(
            adj, whT, e1, e2, mxE, x_part, zPart);
    else
        k_pv1<2048><<<dim3(1, N_ / 64, B_ * H_), dim3(256), 0, stream>>>(
            adj, whT, e1, e2, mxE, x_part, zPart);
    k_wh2<<<dim3(B_ * N_ / 4), dim3(256), 0, stream>>>(
        x_part, zPart, W_last, a_last, wh2, g1, g2, S);
    k_out<<<dim3(B_ * N_ / 4), dim3(256), 0, stream>>>(
        adj, wh2, g1, g2, (float*)d_out);
}

// Round 8
// 100.177 us; speedup vs baseline: 1.6213x; 1.6213x over previous
//
#include <hip/hip_runtime.h>
#include <hip/hip_bf16.h>
#include <cstdint>
#include <cstddef>

#define B_ 2
#define N_ 2048
#define D_ 256
#define H_ 8
#define HID_ 64
#define EN_ 2
#define ALPHA 0.2f
#define NEGBIG (-3.0e38f)
#define LOG2E 1.4426950408889634f

typedef __bf16 bf16x8 __attribute__((ext_vector_type(8)));
typedef float f32x4 __attribute__((ext_vector_type(4)));
typedef unsigned short ushort8 __attribute__((ext_vector_type(8)));
typedef float float4v __attribute__((ext_vector_type(4)));
typedef float float2v __attribute__((ext_vector_type(2)));

__device__ __forceinline__ unsigned short f2bf(float f) {
    unsigned int u = __builtin_bit_cast(unsigned int, f);
    unsigned int r = u + 0x7FFFu + ((u >> 16) & 1u);  // RNE
    return (unsigned short)(r >> 16);
}
__device__ __forceinline__ float bf2f(unsigned short u) {
    unsigned int x = ((unsigned int)u) << 16;
    return __builtin_bit_cast(float, x);
}
__device__ __forceinline__ float leakyf(float x) { return fmaxf(x, ALPHA * x); }

// load 8 consecutive f32, convert to 8 bf16
__device__ __forceinline__ ushort8 cvt8(const float* __restrict__ p) {
    float4v x0 = *(const float4v*)p;
    float4v x1 = *(const float4v*)(p + 4);
    ushort8 r;
    #pragma unroll
    for (int e = 0; e < 4; ++e) { r[e] = f2bf(x0[e]); r[e + 4] = f2bf(x1[e]); }
    return r;
}

// ---------- K0: transpose W_att[h][d][o] f32 -> WT[h][o][d] bf16 (tiny) ----------
__global__ void k_transpose_w(const float* __restrict__ W,
                              unsigned short* __restrict__ WT) {
    int h = blockIdx.x;
    const float* Wh = W + (size_t)h * D_ * HID_;
    unsigned short* WTh = WT + (size_t)h * HID_ * D_;
    for (int idx = threadIdx.x; idx < D_ * HID_; idx += blockDim.x) {
        int d = idx / HID_, o = idx % HID_;
        WTh[o * D_ + d] = f2bf(Wh[idx]);
    }
}

// ---------- K1: wh = fea @ W_att (per b,h), fused e1/e2 (scaled by LOG2E) ----------
__global__ __launch_bounds__(256) void k_wh(
    const float* __restrict__ fea,            // [B][N][D] f32
    const unsigned short* __restrict__ WT,    // [H][64][256] bf16
    const float* __restrict__ a_att,          // [H][128] f32
    unsigned short* __restrict__ whT,         // [B][H][64][N] bf16
    float* __restrict__ e1, float* __restrict__ e2)
{
    int bid = blockIdx.x;
    int i0 = (bid & 31) << 6;
    int h  = (bid >> 5) & 7;
    int b  = bid >> 8;

    __shared__ __align__(16) union SmemA {
        struct { unsigned short fa[64 * 72]; unsigned short wt[64 * 72]; } s;
        float tr[64 * 65];
    } u;

    int t = threadIdx.x;
    int lane = t & 63;
    int wv = t >> 6;          // wave id 0..3
    int r = lane & 15, q = lane >> 4;
    int ra = t >> 2;          // staging row 0..63
    int cc = (t & 3) * 16;    // staging col chunk

    f32x4 acc[4] = {};

    const float* fearow = fea + ((size_t)(b * N_ + i0 + ra)) * D_;
    const unsigned short* wtrow = WT + ((size_t)(h * 64 + ra)) * D_;

    for (int d0 = 0; d0 < D_; d0 += 64) {
        *(ushort8*)&u.s.fa[ra * 72 + cc]     = cvt8(fearow + d0 + cc);
        *(ushort8*)&u.s.fa[ra * 72 + cc + 8] = cvt8(fearow + d0 + cc + 8);
        *(ushort8*)&u.s.wt[ra * 72 + cc]     = *(const ushort8*)(wtrow + d0 + cc);
        *(ushort8*)&u.s.wt[ra * 72 + cc + 8] = *(const ushort8*)(wtrow + d0 + cc + 8);
        __syncthreads();
        #pragma unroll
        for (int k0 = 0; k0 < 64; k0 += 32) {
            bf16x8 a = *(const bf16x8*)&u.s.fa[(16 * wv + r) * 72 + k0 + q * 8];
            #pragma unroll
            for (int f = 0; f < 4; ++f) {
                bf16x8 bb = *(const bf16x8*)&u.s.wt[(16 * f + r) * 72 + k0 + q * 8];
                acc[f] = __builtin_amdgcn_mfma_f32_16x16x32_bf16(a, bb, acc[f], 0, 0, 0);
            }
        }
        __syncthreads();
    }

    // e1/e2 epilogue (scaled by LOG2E for exp2-domain softmax downstream)
    float a1v[4], a2v[4];
    #pragma unroll
    for (int f = 0; f < 4; ++f) {
        a1v[f] = a_att[h * 128 + 16 * f + r];
        a2v[f] = a_att[h * 128 + 64 + 16 * f + r];
    }
    #pragma unroll
    for (int rr = 0; rr < 4; ++rr) {
        float s1 = 0.f, s2 = 0.f;
        #pragma unroll
        for (int f = 0; f < 4; ++f) { s1 += acc[f][rr] * a1v[f]; s2 += acc[f][rr] * a2v[f]; }
        #pragma unroll
        for (int m = 1; m < 16; m <<= 1) {
            s1 += __shfl_xor(s1, m, 64);
            s2 += __shfl_xor(s2, m, 64);
        }
        if (r == 0) {
            int i = i0 + 16 * wv + 4 * q + rr;
            size_t idx = ((size_t)(b * H_ + h)) * N_ + i;
            e1[idx] = s1 * LOG2E; e2[idx] = s2 * LOG2E;
        }
    }

    // transpose wh tile -> whT (via LDS)
    #pragma unroll
    for (int f = 0; f < 4; ++f)
        #pragma unroll
        for (int rr = 0; rr < 4; ++rr)
            u.tr[(16 * f + r) * 65 + 16 * wv + 4 * q + rr] = acc[f][rr];
    __syncthreads();
    {
        int o = t >> 2;
        int ch = (t & 3) * 16;
        unsigned short tmp[16];
        #pragma unroll
        for (int e = 0; e < 16; ++e) tmp[e] = f2bf(u.tr[o * 65 + ch + e]);
        ushort8* dst = (ushort8*)(whT + (((size_t)(b * H_ + h) * 64 + o)) * N_ + i0 + ch);
        dst[0] = *(ushort8*)&tmp[0];
        dst[1] = *(ushort8*)&tmp[8];
    }
}

// ---------- K2: maxE2[bh] = max_j e2[bh][j] (tiny) ----------
__global__ __launch_bounds__(256) void k_maxe2(const float* __restrict__ e2,
                                               float* __restrict__ mx) {
    int bh = blockIdx.x;
    int t = threadIdx.x;
    const float* row = e2 + (size_t)bh * N_;
    float M = NEGBIG;
    #pragma unroll
    for (int it = 0; it < N_ / 256; ++it) M = fmaxf(M, row[it * 256 + t]);
    #pragma unroll
    for (int s = 1; s < 64; s <<= 1) M = fmaxf(M, __shfl_xor(M, s, 64));
    __shared__ float red[4];
    if ((t & 63) == 0) red[t >> 6] = M;
    __syncthreads();
    if (t == 0) mx[bh] = fmaxf(fmaxf(red[0], red[1]), fmaxf(red[2], red[3]));
}

// ---------- K3: x_part[s] = P_chunk @ wh ----------
// 4 waves x 32 rows (M_rep=2) = 128 rows/block. whT dbuf LDS (B-frags read
// once per wave, reused by both M-blocks -> half LDS BW). Separable P-gen:
// p = max(sI*t_j, uI*v_j)*adj, t/v tables in LDS (wave-broadcast reads).
// Counted barrier (lgkmcnt only) keeps global prefetches in flight.
template<int JPER>
__global__ __launch_bounds__(256, 2) void k_pv1(
    const float* __restrict__ adj,
    const unsigned short* __restrict__ whT,   // [B][H][64][N] bf16
    const float* __restrict__ e1g, const float* __restrict__ e2g,
    const float* __restrict__ maxE2,
    unsigned short* __restrict__ x_part,      // [S][B][N][512] bf16
    float* __restrict__ zPart)                // [S][16][N] f32
{
    constexpr int NT = JPER / 64;
    int s  = blockIdx.x;
    int i0 = blockIdx.y << 7;                 // 128 rows per block
    int bh = blockIdx.z;                      // b*H + h
    int h = bh & 7, b = bh >> 3;
    int jBeg = s * JPER;

    __shared__ __align__(16) unsigned short wt_lds[2][64 * 64];  // 2x8 KB swizzled
    __shared__ float tE[JPER];
    __shared__ float vE[JPER];

    int t = threadIdx.x;
    int lane = t & 63;
    int wv = t >> 6;                          // 0..3
    int r = lane & 15, q = lane >> 4;

    // two P rows per lane (M_rep=2)
    int ir0 = i0 + wv * 32 + r;
    int ir1 = ir0 + 16;
    float mx = maxE2[bh];
    float e1_0 = e1g[(size_t)bh * N_ + ir0];
    float e1_1 = e1g[(size_t)bh * N_ + ir1];
    float m0 = leakyf(e1_0 + mx), m1 = leakyf(e1_1 + mx);
    float sI0 = __builtin_amdgcn_exp2f(e1_0 - m0);
    float uI0 = __builtin_amdgcn_exp2f(ALPHA * e1_0 - m0);
    float sI1 = __builtin_amdgcn_exp2f(e1_1 - m1);
    float uI1 = __builtin_amdgcn_exp2f(ALPHA * e1_1 - m1);

    const float* e2p = e2g + (size_t)bh * N_ + jBeg;
    const float* ap0 = adj + ((size_t)(b * N_ + ir0)) * N_ + jBeg + q * 8;
    const float* ap1 = ap0 + (size_t)16 * N_;

    // whT staging: 2 chunks per thread (c = t, t+256); chunk c covers
    // row o=c>>3, j-chunk (c&7)*8; dest XOR-swizzled.
    int c0 = t, c1 = t + 256;
    const unsigned short* wsrc0 =
        whT + ((size_t)bh * 64 + (c0 >> 3)) * N_ + jBeg + (c0 & 7) * 8;
    const unsigned short* wsrc1 =
        whT + ((size_t)bh * 64 + (c1 >> 3)) * N_ + jBeg + (c1 & 7) * 8;
    int woff0 = (c0 * 8) ^ (((c0 >> 3) & 7) << 3);
    int woff1 = (c1 * 8) ^ (((c1 >> 3) & 7) << 3);

    int swz = (r & 7) << 3;
    int koff0 = (8 * q) ^ swz;
    int koff1 = (32 + 8 * q) ^ swz;

    bf16x8 ones;
    #pragma unroll
    for (int e = 0; e < 8; ++e) ones[e] = (__bf16)1.0f;

    f32x4 acc[2][4] = {};
    f32x4 accz[2] = {};

    // adj register pipeline (2-deep): 8 float4v per set (2 rows x 4 chunks)
    float4v aA[8], aB[8];
    // whT stage regs (1-deep): tile t8+1
    ushort8 wN0, wN1;

#define LOADADJ(A, tile) do {                                                   \
        const float* p0 = ap0 + (tile) * 64;                                    \
        const float* p1 = ap1 + (tile) * 64;                                    \
        A[0] = *(const float4v*)(p0);      A[1] = *(const float4v*)(p0 + 4);    \
        A[2] = *(const float4v*)(p0 + 32); A[3] = *(const float4v*)(p0 + 36);   \
        A[4] = *(const float4v*)(p1);      A[5] = *(const float4v*)(p1 + 4);    \
        A[6] = *(const float4v*)(p1 + 32); A[7] = *(const float4v*)(p1 + 36);   \
    } while (0)
#define LOADW(tile) do {                                                        \
        wN0 = *(const ushort8*)(wsrc0 + (tile) * 64);                           \
        wN1 = *(const ushort8*)(wsrc1 + (tile) * 64);                           \
    } while (0)

    // prologue: t/v tables; tile0 -> buf0; tile1 -> wN regs; adj tiles 0,1
    for (int jj = t; jj < JPER; jj += 256) {
        float ev = e2p[jj];
        tE[jj] = __builtin_amdgcn_exp2f(ev);
        vE[jj] = __builtin_amdgcn_exp2f(ALPHA * ev);
    }
    LOADW(0);
    *(ushort8*)&wt_lds[0][woff0] = wN0;
    *(ushort8*)&wt_lds[0][woff1] = wN1;
    if (NT > 1) LOADW(1);
    LOADADJ(aA, 0);
    if (NT > 1) LOADADJ(aB, 1);
    asm volatile("s_waitcnt lgkmcnt(0)" ::: "memory");
    __builtin_amdgcn_s_barrier();

    // separable P-gen into MFMA A-fragments
    auto pgen = [&](const float4v* av, float sI, float uI,
                    const float4v& t0, const float4v& t1,
                    const float4v& t2, const float4v& t3,
                    const float4v& v0, const float4v& v1,
                    const float4v& v2, const float4v& v3,
                    bf16x8& pa0, bf16x8& pa1) {
        #pragma unroll
        for (int e = 0; e < 4; ++e) {
            pa0[e]     = (__bf16)(fmaxf(sI * t0[e], uI * v0[e]) * av[0][e]);
            pa0[e + 4] = (__bf16)(fmaxf(sI * t1[e], uI * v1[e]) * av[1][e]);
            pa1[e]     = (__bf16)(fmaxf(sI * t2[e], uI * v2[e]) * av[2][e]);
            pa1[e + 4] = (__bf16)(fmaxf(sI * t3[e], uI * v3[e]) * av[3][e]);
        }
    };

    #pragma unroll 2
    for (int t8 = 0; t8 < NT; ++t8) {
        const int cur = t8 & 1;
        // stage tile t8+1 (regs loaded last iter) into other buffer
        if (t8 + 1 < NT) {
            *(ushort8*)&wt_lds[cur ^ 1][woff0] = wN0;
            *(ushort8*)&wt_lds[cur ^ 1][woff1] = wN1;
        }
        // issue whT loads for tile t8+2
        if (t8 + 2 < NT) LOADW(t8 + 2);

        // t/v tile slices (wave-broadcast LDS reads, shared by both M-blocks)
        const float* tb = &tE[t8 * 64 + q * 8];
        const float* vb = &vE[t8 * 64 + q * 8];
        float4v t0 = *(const float4v*)(tb),      t1 = *(const float4v*)(tb + 4);
        float4v t2 = *(const float4v*)(tb + 32), t3 = *(const float4v*)(tb + 36);
        float4v v0 = *(const float4v*)(vb),      v1 = *(const float4v*)(vb + 4);
        float4v v2 = *(const float4v*)(vb + 32), v3 = *(const float4v*)(vb + 36);

        bf16x8 pa00, pa01, pa10, pa11;
        if (cur == 0) {
            pgen(aA,     sI0, uI0, t0, t1, t2, t3, v0, v1, v2, v3, pa00, pa01);
            pgen(aA + 4, sI1, uI1, t0, t1, t2, t3, v0, v1, v2, v3, pa10, pa11);
        } else {
            pgen(aB,     sI0, uI0, t0, t1, t2, t3, v0, v1, v2, v3, pa00, pa01);
            pgen(aB + 4, sI1, uI1, t0, t1, t2, t3, v0, v1, v2, v3, pa10, pa11);
        }
        // issue adj loads for tile t8+2 into the just-freed set
        if (t8 + 2 < NT) {
            if (cur == 0) LOADADJ(aA, t8 + 2);
            else          LOADADJ(aB, t8 + 2);
        }

        // B-frags read once, used by both M-blocks
        const unsigned short* Wb = wt_lds[cur];
        bf16x8 bb0[4], bb1[4];
        #pragma unroll
        for (int f = 0; f < 4; ++f) {
            bb0[f] = *(const bf16x8*)&Wb[f * 1024 + r * 64 + koff0];
            bb1[f] = *(const bf16x8*)&Wb[f * 1024 + r * 64 + koff1];
        }
        #pragma unroll
        for (int f = 0; f < 4; ++f) {
            acc[0][f] = __builtin_amdgcn_mfma_f32_16x16x32_bf16(pa00, bb0[f], acc[0][f], 0, 0, 0);
            acc[1][f] = __builtin_amdgcn_mfma_f32_16x16x32_bf16(pa10, bb0[f], acc[1][f], 0, 0, 0);
        }
        accz[0] = __builtin_amdgcn_mfma_f32_16x16x32_bf16(pa00, ones, accz[0], 0, 0, 0);
        accz[1] = __builtin_amdgcn_mfma_f32_16x16x32_bf16(pa10, ones, accz[1], 0, 0, 0);
        #pragma unroll
        for (int f = 0; f < 4; ++f) {
            acc[0][f] = __builtin_amdgcn_mfma_f32_16x16x32_bf16(pa01, bb1[f], acc[0][f], 0, 0, 0);
            acc[1][f] = __builtin_amdgcn_mfma_f32_16x16x32_bf16(pa11, bb1[f], acc[1][f], 0, 0, 0);
        }
        accz[0] = __builtin_amdgcn_mfma_f32_16x16x32_bf16(pa01, ones, accz[0], 0, 0, 0);
        accz[1] = __builtin_amdgcn_mfma_f32_16x16x32_bf16(pa11, ones, accz[1], 0, 0, 0);

        // counted barrier: drain LDS ops only; global prefetches stay in flight
        asm volatile("s_waitcnt lgkmcnt(0)" ::: "memory");
        __builtin_amdgcn_s_barrier();
    }
#undef LOADADJ
#undef LOADW

    // epilogue: bf16 raw partial write (elu + /Z happen in k_wh2)
    unsigned short* xp = x_part + ((size_t)s * (B_ * N_) + (size_t)b * N_) * 512 + h * 64;
    #pragma unroll
    for (int mR = 0; mR < 2; ++mR) {
        #pragma unroll
        for (int f = 0; f < 4; ++f) {
            #pragma unroll
            for (int rr = 0; rr < 4; ++rr) {
                int i = i0 + wv * 32 + mR * 16 + 4 * q + rr;
                xp[(size_t)i * 512 + 16 * f + r] = f2bf(acc[mR][f][rr]);
            }
        }
        if (r == 0) {
            #pragma unroll
            for (int rr = 0; rr < 4; ++rr) {
                int i = i0 + wv * 32 + mR * 16 + 4 * q + rr;
                zPart[((size_t)(s * 16 + bh)) * N_ + i] = accz[mR][rr];
            }
        }
    }
}

// ---------- K4: x = elu(sum_s part / Z); wh2 = x @ W_last; g1/g2 scaled ----------
__global__ __launch_bounds__(256) void k_wh2(
    const unsigned short* __restrict__ x_part,  // bf16
    const float* __restrict__ zPart,
    const float* __restrict__ W_last,  // [512][2] f32
    const float* __restrict__ a_last,  // [4] f32
    float* __restrict__ wh2, float* __restrict__ g1, float* __restrict__ g2,
    int S)
{
    int idx = blockIdx.x * 4 + (threadIdx.x >> 6);  // b*N + n
    int lane = threadIdx.x & 63;
    int b = idx >> 11, n = idx & (N_ - 1);
    float a0 = 0.f, a1 = 0.f;
    #pragma unroll
    for (int it = 0; it < 8; ++it) {        // it == head index
        int k = it * 64 + lane;
        float xv = 0.f, zv = 0.f;
        for (int s = 0; s < S; ++s) {
            xv += bf2f(x_part[((size_t)s * (B_ * N_) + idx) * 512 + k]);
            zv += zPart[((size_t)(s * 16 + b * 8 + it)) * N_ + n];
        }
        float x = (zv > 0.f) ? xv / zv : 0.f;
        x = x > 0.f ? x : expm1f(x);
        float2v wl = *(const float2v*)(W_last + k * 2);
        a0 += x * wl[0];
        a1 += x * wl[1];
    }
    #pragma unroll
    for (int s = 1; s < 64; s <<= 1) {
        a0 += __shfl_xor(a0, s, 64);
        a1 += __shfl_xor(a1, s, 64);
    }
    if (lane == 0) {
        wh2[idx * 2] = a0; wh2[idx * 2 + 1] = a1;
        g1[idx] = (a0 * a_last[0] + a1 * a_last[1]) * LOG2E;
        g2[idx] = (a0 * a_last[2] + a1 * a_last[3]) * LOG2E;
    }
}

// ---------- K5: final attention + elu, two-pass register version (exp2) ----------
__global__ __launch_bounds__(256) void k_out(
    const float* __restrict__ adj,
    const float* __restrict__ wh2,
    const float* __restrict__ g1, const float* __restrict__ g2,
    float* __restrict__ out)
{
    int idx = blockIdx.x * 4 + (threadIdx.x >> 6); // b*N + i
    int lane = threadIdx.x & 63;
    int b = idx >> 11;
    float gi = g1[idx];
    const float* arow = adj + (size_t)idx * N_;
    const float* g2b = g2 + (size_t)b * N_;
    const float* wh2b = wh2 + (size_t)b * N_ * 2;

    float ep[32];
    float M = NEGBIG;
    #pragma unroll
    for (int it = 0; it < 8; ++it) {
        int j = it * 256 + lane * 4;
        float4v a4 = *(const float4v*)(arow + j);
        float4v s4 = *(const float4v*)(g2b + j);
        #pragma unroll
        for (int e = 0; e < 4; ++e) {
            float l = leakyf(gi + s4[e]);
            float v = (a4[e] != 0.f) ? l : NEGBIG;
            ep[it * 4 + e] = v;
            M = fmaxf(M, v);
        }
    }
    #pragma unroll
    for (int s = 1; s < 64; s <<= 1) M = fmaxf(M, __shfl_xor(M, s, 64));

    float Z = 0.f, A0 = 0.f, A1 = 0.f;
    #pragma unroll
    for (int it = 0; it < 8; ++it) {
        int j = it * 256 + lane * 4;
        float4v wA = *(const float4v*)(wh2b + 2 * j);
        float4v wB = *(const float4v*)(wh2b + 2 * j + 4);
        #pragma unroll
        for (int e = 0; e < 4; ++e) {
            float p = __builtin_amdgcn_exp2f(ep[it * 4 + e] - M);
            Z += p;
            float w0 = (e < 2) ? wA[2 * e] : wB[2 * (e - 2)];
            float w1 = (e < 2) ? wA[2 * e + 1] : wB[2 * (e - 2) + 1];
            A0 += p * w0;
            A1 += p * w1;
        }
    }
    #pragma unroll
    for (int s = 1; s < 64; s <<= 1) {
        Z += __shfl_xor(Z, s, 64);
        A0 += __shfl_xor(A0, s, 64);
        A1 += __shfl_xor(A1, s, 64);
    }
    if (lane == 0) {
        float o0 = A0 / Z, o1 = A1 / Z;
        o0 = o0 > 0.f ? o0 : expm1f(o0);
        o1 = o1 > 0.f ? o1 : expm1f(o1);
        float2v ov; ov[0] = o0; ov[1] = o1;
        *(float2v*)(out + idx * 2) = ov;
    }
}

extern "C" void kernel_launch(void* const* d_in, const int* in_sizes, int n_in,
                              void* d_out, int out_size, void* d_ws, size_t ws_size,
                              hipStream_t stream) {
    const float* fea    = (const float*)d_in[0];
    const float* adj    = (const float*)d_in[1];
    const float* W_att  = (const float*)d_in[2];
    const float* a_att  = (const float*)d_in[3];
    const float* W_last = (const float*)d_in[4];
    const float* a_last = (const float*)d_in[5];

    char* ws = (char*)d_ws;
    // layout (bytes)
    float* e1  = (float*)(ws + 0);                            // 131,072
    float* e2  = (float*)(ws + 131072);                       // 131,072
    float* mxE = (float*)(ws + 262144);                       // 256 (pad)
    float* wh2 = (float*)(ws + 262400);                       // 32,768
    float* g1  = (float*)(ws + 295168);                       // 16,384
    float* g2  = (float*)(ws + 311552);                       // 16,384
    unsigned short* WT  = (unsigned short*)(ws + 327936);     // 262,144
    unsigned short* whT = (unsigned short*)(ws + 590080);     // 4,194,304
    float* zPart = (float*)(ws + 4784384);                    // 524,288 (S<=4)
    unsigned short* x_part = (unsigned short*)(ws + 5308672); // S * 4,194,304 (bf16)

    const size_t BASE = 5308672ULL, XPART = 4194304ULL;
    int S = (ws_size >= BASE + 4 * XPART) ? 4
          : (ws_size >= BASE + 2 * XPART) ? 2 : 1;

    k_transpose_w<<<dim3(H_), dim3(256), 0, stream>>>(W_att, WT);
    k_wh<<<dim3(B_ * H_ * (N_ / 64)), dim3(256), 0, stream>>>(
        fea, WT, a_att, whT, e1, e2);
    k_maxe2<<<dim3(B_ * H_), dim3(256), 0, stream>>>(e2, mxE);
    if (S == 4)
        k_pv1<512><<<dim3(4, N_ / 128, B_ * H_), dim3(256), 0, stream>>>(
            adj, whT, e1, e2, mxE, x_part, zPart);
    else if (S == 2)
        k_pv1<1024><<<dim3(2, N_ / 128, B_ * H_), dim3(256), 0, stream>>>(
            adj, whT, e1, e2, mxE, x_part, zPart);
    else
        k_pv1<2048><<<dim3(1, N_ / 128, B_ * H_), dim3(256), 0, stream>>>(
            adj, whT, e1, e2, mxE, x_part, zPart);
    k_wh2<<<dim3(B_ * N_ / 4), dim3(256), 0, stream>>>(
        x_part, zPart, W_last, a_last, wh2, g1, g2, S);
    k_out<<<dim3(B_ * N_ / 4), dim3(256), 0, stream>>>(
        adj, wh2, g1, g2, (float*)d_out);
}